// Round 8
// baseline (310.633 us; speedup 1.0000x reference)
//
#include <hip/hip_runtime.h>
#include <hip/hip_bf16.h>

#define DIN 128
#define HID1 128
#define HID2 64
#define OUTD 40
#define NCHUNK 128  // edge chunks for LDS-histogram CSR build (6250 edges/chunk)

typedef __attribute__((ext_vector_type(8))) short bf16x8;
typedef __attribute__((ext_vector_type(4))) float f32x4;

__device__ __forceinline__ float bf2f(unsigned int u) {
    union { unsigned int i; float f; } c;
    c.i = u << 16;
    return c.f;
}
__device__ __forceinline__ unsigned short f2bf(float f) {
    union { float f; unsigned int i; } c; c.f = f;
    unsigned int r = c.i + 0x7FFFu + ((c.i >> 16) & 1u);   // RNE
    return (unsigned short)(r >> 16);
}
__device__ __forceinline__ unsigned int packbf(float lo, float hi) {
    return (unsigned int)f2bf(lo) | ((unsigned int)f2bf(hi) << 16);
}

__device__ __forceinline__ int get_src(const int* ei, int E, int e, int e64) {
    return e64 ? ei[2 * e] : ei[e];
}
__device__ __forceinline__ int get_dst(const int* ei, int E, int e, int e64) {
    return e64 ? ei[2 * (E + e)] : ei[E + e];
}

// ---------------- weight conversion descriptor ----------------
struct WCvt {
    const void* p[14];
    int sz[14];
    int off[14];
    int tobf[14];
    int cols[14];
};

// ---------------- posA (+flags): CSR histogram, zero global atomics ----------------
// blocks 0..NCHUNK-1: per-chunk LDS histogram (packed 2x16-bit counters/u32 word).
//   1024 threads, 6250 edges/block -> ~6 serial edge iterations (the R1->R3 A/B
//   showed the per-block serial chain, not CU count, gates this kernel).
// block NCHUNK: dtype detect -> flags[0] (x f32?), flags[1] (edges int64?).
__launch_bounds__(1024)
__global__ void posA_kernel(const unsigned short* __restrict__ xu,
                            const int* __restrict__ ei,
                            int* __restrict__ flags,
                            int* __restrict__ pos,
                            unsigned int* __restrict__ hist,
                            int E, int N) {
    __shared__ unsigned int h32[25000];          // (N+1)/2 words, N<=50000
    __shared__ int sh2[2];
    const int NW = (N + 1) >> 1;
    const int b = blockIdx.x;
    const int t = threadIdx.x;
    if (b < NCHUNK) {
        if (t == 0) sh2[0] = 0;
        for (int w = t; w < NW; w += 1024) h32[w] = 0u;
        __syncthreads();
        // local int64 detect: high words of int64 edge values are ~all zero
        int zodd = 0;
        for (int k = t; k < 1024; k += 1024)
            if (ei[2 * k + 1] == 0) zodd++;
        if (zodd) atomicAdd(&sh2[0], zodd);
        __syncthreads();
        const int e64 = (sh2[0] > 512) ? 1 : 0;
        const int CH = (E + NCHUNK - 1) / NCHUNK;
        const int lo = b * CH;
        int hi = lo + CH; if (hi > E) hi = E;
        for (int e = lo + t; e < hi; e += 1024) {
            int d = e64 ? ei[2 * (E + e)] : ei[E + e];
            if ((unsigned)d < (unsigned)N) {
                unsigned sh = (unsigned)(d & 1) << 4;
                unsigned old = atomicAdd(&h32[d >> 1], 1u << sh);
                pos[e] = (int)((old >> sh) & 0xffffu);
            } else {
                pos[e] = -1;
            }
        }
        __syncthreads();
        unsigned int* hb = hist + (size_t)b * NW;
        for (int w = t; w < NW; w += 1024) hb[w] = h32[w];
    } else {
        // flags for downstream kernels
        if (t < 2) sh2[t] = 0;
        __syncthreads();
        int bad = 0;
        for (int k = t; k < 2048; k += 1024) {
            float v = bf2f(xu[2 * k]);
            float a = fabsf(v);
            if (!(a <= 1e4f) || (v != 0.f && a < 1e-4f)) bad++;
        }
        int zodd = 0;
        for (int k = t; k < 1024; k += 1024)
            if (ei[2 * k + 1] == 0) zodd++;
        if (bad) atomicAdd(&sh2[0], bad);
        if (zodd) atomicAdd(&sh2[1], zodd);
        __syncthreads();
        if (t == 0) {
            flags[0] = (sh2[0] > 512) ? 1 : 0;
            flags[1] = (sh2[1] > 512) ? 1 : 0;
        }
    }
}

// phaseB (+wcvt fat blocks): per-node exclusive scan across chunks -> basev, cnt;
// reduces its 512-node range into bsum entries 2b, 2b+1.
// basev is PACKED 2x16-bit (same word layout as hist).
// blocks >= PB: weight conversion (tobf=1 -> bf16 arena TRANSPOSED; else f32 arena).
__launch_bounds__(256)
__global__ void phaseB_kernel(const unsigned int* __restrict__ hist,
                              unsigned int* __restrict__ basev,
                              int* __restrict__ cnt, int* __restrict__ bsum,
                              int N, int PB,
                              WCvt wc, unsigned short* __restrict__ wbf,
                              float* __restrict__ wf,
                              const int* __restrict__ flags) {
    __shared__ int red[256];
    const int NW = (N + 1) >> 1;
    int t = threadIdx.x;
    int blk = blockIdx.x;
    if (blk < PB) {
        int w = blk * 256 + t;
        unsigned run0 = 0, run1 = 0;
        if (w < NW) {
            #pragma unroll 4
            for (int b = 0; b < NCHUNK; ++b) {
                unsigned u = hist[(size_t)b * NW + w];
                basev[(size_t)b * NW + w] = (run0 & 0xffffu) | (run1 << 16);
                run0 += u & 0xffffu;
                run1 += u >> 16;
            }
            cnt[2 * w] = (int)run0;
            if (2 * w + 1 < N) cnt[2 * w + 1] = (int)run1;
        }
        int tot = 0;
        if (w < NW) tot = (int)run0 + ((2 * w + 1 < N) ? (int)run1 : 0);
        red[t] = tot;
        __syncthreads();
        #pragma unroll
        for (int off = 64; off >= 1; off >>= 1) {
            if ((t & 127) < off) red[t] += red[t + off];
            __syncthreads();
        }
        if (t == 0) bsum[2 * blk] = red[0];
        if (t == 128) bsum[2 * blk + 1] = red[128];
    } else {
        int xf32 = flags[0];
        int stride = (gridDim.x - PB) * 256;
        int tid = (blk - PB) * 256 + t;
        for (int a = 0; a < 14; ++a) {
            const float* pf = (const float*)wc.p[a];
            const unsigned short* pb = (const unsigned short*)wc.p[a];
            int n = wc.sz[a], off = wc.off[a], tobf = wc.tobf[a];
            int cols = wc.cols[a];
            int rows = tobf ? (n / cols) : 0;
            for (int i = tid; i < n; i += stride) {
                float v = xf32 ? pf[i] : bf2f(pb[i]);
                if (tobf) {
                    int k = i / cols, m = i % cols;
                    wbf[off + m * rows + k] = f2bf(v);   // transposed
                } else {
                    wf[off + i] = v;
                }
            }
        }
    }
}

// emit (+inline bscan): each block scans bsum (<=256 entries) in LDS for its base,
// then per-node prefix -> indptr, dinv. Last block writes indptr[N].
__launch_bounds__(256)
__global__ void emit_kernel(const int* __restrict__ cnt, const int* __restrict__ bsum,
                            int* __restrict__ indptr, float* __restrict__ dinv,
                            int N, int NB) {
    __shared__ int part[256];
    __shared__ int sh[256];
    int t = threadIdx.x;
    part[t] = (t < NB) ? bsum[t] : 0;
    __syncthreads();
    for (int off = 1; off < 256; off <<= 1) {
        int v = (t >= off) ? part[t - off] : 0;
        __syncthreads();
        part[t] += v;
        __syncthreads();
    }
    int bbase = (blockIdx.x > 0) ? part[blockIdx.x - 1] : 0;
    int total = part[255];
    int i = blockIdx.x * 256 + t;
    int c = (i < N) ? cnt[i] : 0;
    sh[t] = c;
    __syncthreads();
    for (int off = 1; off < 256; off <<= 1) {
        int v = (t >= off) ? sh[t - off] : 0;
        __syncthreads();
        sh[t] += v;
        __syncthreads();
    }
    if (i < N) {
        int excl = sh[t] - c + bbase;
        indptr[i] = excl;
        dinv[i] = 1.0f / sqrtf((float)(c + 1));   // +1 self loop
    }
    if (blockIdx.x == (unsigned)(NB - 1) && t == 0) indptr[N] = total;
}

// atomic-free scatter: slot = indptr[dst] + basev[chunk][dst](packed u16) + pos[e].
__global__ void scatter_kernel(const int* __restrict__ ei, const int* __restrict__ indptr,
                               const int* __restrict__ pos, const float* __restrict__ dinv,
                               const unsigned int* __restrict__ basev,
                               int2* __restrict__ csr_sn,
                               int E, int N, const int* __restrict__ flags) {
    int e64 = flags[1];
    int CH = (E + NCHUNK - 1) / NCHUNK;
    int NW = (N + 1) >> 1;
    int base = (blockIdx.x * blockDim.x + threadIdx.x) * 4;
    #pragma unroll
    for (int u = 0; u < 4; ++u) {
        int e = base + u;
        if (e < E) {
            int p = pos[e];
            if (p >= 0) {
                int bb = e / CH;
                int d = get_dst(ei, E, e, e64);
                int s = get_src(ei, E, e, e64);
                if ((unsigned)s >= (unsigned)N) s = 0;
                float nrm = dinv[s] * dinv[d];
                unsigned bw = basev[(size_t)bb * NW + (d >> 1)];
                int bval = (d & 1) ? (int)(bw >> 16) : (int)(bw & 0xffffu);
                int slot = indptr[d] + bval + p;
                csr_sn[slot] = make_int2(s, __float_as_int(nrm));
            }
        }
    }
}

// ---------------- MFMA matmul: C[N,M](bf16) = A[N,K] x W[K,M](bf16) ----------------

template<typename AT>
__device__ __forceinline__ bf16x8 ld_afrag(const AT* p);
template<>
__device__ __forceinline__ bf16x8 ld_afrag<unsigned short>(const unsigned short* p) {
    return *(const bf16x8*)p;
}
template<>
__device__ __forceinline__ bf16x8 ld_afrag<float>(const float* p) {
    float4 a = *(const float4*)p;
    float4 b = *(const float4*)(p + 4);
    bf16x8 r;
    r[0] = (short)f2bf(a.x); r[1] = (short)f2bf(a.y);
    r[2] = (short)f2bf(a.z); r[3] = (short)f2bf(a.w);
    r[4] = (short)f2bf(b.x); r[5] = (short)f2bf(b.y);
    r[6] = (short)f2bf(b.z); r[7] = (short)f2bf(b.w);
    return r;
}

template<int K, int M, typename AT>
__device__ __forceinline__ void mm_body(const AT* __restrict__ A,
                                        const unsigned short* __restrict__ WT,
                                        unsigned short* __restrict__ C, int N,
                                        unsigned short (*Ws)[K + 8]) {
    int tid = threadIdx.x;
    for (int idx = tid; idx < M * K / 8; idx += 256) {
        int r = idx / (K / 8), c8 = idx % (K / 8);
        *(uint4*)&Ws[r][c8 * 8] = *(const uint4*)&WT[r * K + c8 * 8];
    }
    __syncthreads();
    int w = tid >> 6, lane = tid & 63;
    int m = lane & 15, q = lane >> 4;
    int row_a = blockIdx.x * 64 + w * 16 + m;
    if (row_a >= N) row_a = N - 1;              // clamp; garbage rows masked at store
    const AT* arow = A + (size_t)row_a * K;
    f32x4 acc[M / 16];
    #pragma unroll
    for (int t = 0; t < M / 16; ++t) acc[t] = (f32x4){0.f, 0.f, 0.f, 0.f};
    #pragma unroll
    for (int ks = 0; ks < K / 32; ++ks) {
        int k0 = ks * 32 + q * 8;
        bf16x8 a = ld_afrag<AT>(arow + k0);
        #pragma unroll
        for (int t = 0; t < M / 16; ++t) {
            bf16x8 b = *(const bf16x8*)&Ws[t * 16 + m][k0];
            acc[t] = __builtin_amdgcn_mfma_f32_16x16x32_bf16(a, b, acc[t], 0, 0, 0);
        }
    }
    int rbase = blockIdx.x * 64 + w * 16 + q * 4;
    #pragma unroll
    for (int reg = 0; reg < 4; ++reg) {
        int row = rbase + reg;
        if (row < N) {
            #pragma unroll
            for (int t = 0; t < M / 16; ++t)
                C[(size_t)row * M + t * 16 + m] = f2bf(acc[t][reg]);
        }
    }
}

// layer 1: runtime dtype dispatch (uniform branch), single launch
template<int K, int M>
__launch_bounds__(256)
__global__ void mm_dual_kernel(const void* __restrict__ A,
                               const unsigned short* __restrict__ WT,
                               unsigned short* __restrict__ C, int N,
                               const int* __restrict__ flags) {
    __shared__ unsigned short Ws[M][K + 8];
    if (flags[0]) mm_body<K, M, float>((const float*)A, WT, C, N, Ws);
    else          mm_body<K, M, unsigned short>((const unsigned short*)A, WT, C, N, Ws);
}

// layers 2/3: always bf16 input
template<int K, int M>
__launch_bounds__(256)
__global__ void mm_bf_kernel(const unsigned short* __restrict__ A,
                             const unsigned short* __restrict__ WT,
                             unsigned short* __restrict__ C, int N) {
    __shared__ unsigned short Ws[M][K + 8];
    mm_body<K, M, unsigned short>(A, WT, C, N, Ws);
}

// ---------------- aggregation + optional ReLU/LN ----------------
// ONE NODE PER WAVE: 64 lanes = 4 edge-slots x 16 column-lanes.
// Wave-uniform trip count (no lockstep max-of-4 waste) + 4-edge round
// granularity (zero-pad inflation ~1.13x vs 1.60x for the old 4-node/wave
// 8-edge-round lockstep). 2-stage pipeline: round r+1's row load issues
// while round r accumulates. R6 showed TLP hides gather latency, so issued
// work -- not ILP depth -- is the lever.

template<int VPL>
__device__ __forceinline__ uint4 ld_row(const unsigned short* p) {
    if constexpr (VPL == 8) {
        return *(const uint4*)p;
    } else {
        uint2 t = *(const uint2*)p;
        return make_uint4(t.x, t.y, 0u, 0u);
    }
}

template<int VPL>
__device__ __forceinline__ void acc_row(float* acc, uint4 u, float n) {
    acc[0] += bf2f(u.x & 0xffffu) * n; acc[1] += bf2f(u.x >> 16) * n;
    acc[2] += bf2f(u.y & 0xffffu) * n; acc[3] += bf2f(u.y >> 16) * n;
    if constexpr (VPL == 8) {
        acc[4] += bf2f(u.z & 0xffffu) * n; acc[5] += bf2f(u.z >> 16) * n;
        acc[6] += bf2f(u.w & 0xffffu) * n; acc[7] += bf2f(u.w >> 16) * n;
    }
}

template<int H, bool RELU_LN, bool EMB>
__launch_bounds__(256)
__global__ void agg_kernel(const unsigned short* __restrict__ h,
                           const int* __restrict__ indptr,
                           const int2* __restrict__ csr_sn,
                           const float* __restrict__ dinv,
                           const float* __restrict__ bias,
                           const float* __restrict__ gamma,
                           const float* __restrict__ beta,
                           unsigned short* __restrict__ out,
                           void* __restrict__ out_emb,
                           int N, const int* __restrict__ flags) {
    constexpr int VPL = H / 16;                 // 8 (H=128), 4 (H=64)
    __shared__ int2 lsn[4][64];                 // [wave][edge]
    int w = threadIdx.x >> 6;
    int lane = threadIdx.x & 63;
    int slot = lane >> 4;                       // edge slot within wave
    int idx = lane & 15;                        // column lane within slot
    int node = blockIdx.x * 4 + w;
    bool active = node < N;
    int nd = active ? node : N - 1;             // clamp; inactive waves never store
    float di = dinv[nd];
    int c0 = idx * VPL;
    float acc[VPL];
    #pragma unroll
    for (int v = 0; v < VPL; ++v) acc[v] = 0.f;
    // self loop: slot 0 only (merged in by the cross-slot reduction)
    if (slot == 0)
        acc_row<VPL>(acc, ld_row<VPL>(h + (size_t)nd * H + c0), di * di);
    int beg = indptr[nd], end = indptr[nd + 1];
    for (int base = beg; base < end; base += 64) {
        int m = end - base; if (m > 64) m = 64;
        // coalesced 64-edge staging with zero-norm padding; one event covers
        // deg<=64 (~99.99% of Poisson(16) nodes)
        lsn[w][lane] = (lane < m) ? csr_sn[base + lane] : make_int2(0, 0);
        // same-wave LDS write->read: ordered, no barrier
        int rounds = (m + 3) >> 2;              // 4 edges (1/slot) per round
        int2 e = lsn[w][slot];
        uint4 u = ld_row<VPL>(h + (size_t)e.x * H + c0);
        float n = __int_as_float(e.y);
        for (int r = 1; r < rounds; ++r) {
            int2 e2 = lsn[w][r * 4 + slot];
            uint4 u2 = ld_row<VPL>(h + (size_t)e2.x * H + c0);  // overlap next load
            float n2 = __int_as_float(e2.y);
            acc_row<VPL>(acc, u, n);
            u = u2; n = n2;
        }
        acc_row<VPL>(acc, u, n);
    }
    // merge the 4 edge-slots (every lane ends with the full row sum)
    #pragma unroll
    for (int v = 0; v < VPL; ++v) {
        acc[v] += __shfl_xor(acc[v], 16, 64);
        acc[v] += __shfl_xor(acc[v], 32, 64);
    }
    #pragma unroll
    for (int v = 0; v < VPL; ++v) acc[v] += bias[c0 + v];
    if constexpr (RELU_LN) {
        #pragma unroll
        for (int v = 0; v < VPL; ++v) acc[v] = fmaxf(acc[v], 0.f);
        float s = 0.f, sq = 0.f;
        #pragma unroll
        for (int v = 0; v < VPL; ++v) { s += acc[v]; sq += acc[v] * acc[v]; }
        #pragma unroll
        for (int off = 8; off >= 1; off >>= 1) {   // stays inside the 16-lane group
            s += __shfl_xor(s, off, 64);
            sq += __shfl_xor(sq, off, 64);
        }
        float mu = s * (1.0f / H);
        float var = fmaxf(sq * (1.0f / H) - mu * mu, 0.f);
        float inv = 1.0f / sqrtf(var + 1e-5f);
        #pragma unroll
        for (int v = 0; v < VPL; ++v)
            acc[v] = (acc[v] - mu) * inv * gamma[c0 + v] + beta[c0 + v];
    }
    if (active && slot == 0) {
        unsigned short* orow = out + (size_t)node * H + c0;
        if constexpr (VPL == 8) {
            uint4 p;
            p.x = packbf(acc[0], acc[1]); p.y = packbf(acc[2], acc[3]);
            p.z = packbf(acc[4], acc[5]); p.w = packbf(acc[6], acc[7]);
            *(uint4*)orow = p;
        } else {
            uint2 p; p.x = packbf(acc[0], acc[1]); p.y = packbf(acc[2], acc[3]);
            *(uint2*)orow = p;
        }
        if constexpr (EMB) {
            if (flags[0]) {
                float* o = (float*)out_emb + (size_t)node * H + c0;
                #pragma unroll
                for (int v4 = 0; v4 < VPL / 4; ++v4)
                    *(float4*)(o + v4 * 4) = make_float4(acc[v4 * 4], acc[v4 * 4 + 1],
                                                         acc[v4 * 4 + 2], acc[v4 * 4 + 3]);
            } else {
                unsigned short* o = (unsigned short*)out_emb + (size_t)node * H + c0;
                #pragma unroll
                for (int v2 = 0; v2 < VPL / 2; ++v2)
                    ((unsigned int*)o)[v2] = packbf(acc[v2 * 2], acc[v2 * 2 + 1]);
            }
        }
    }
}

// ---------------- post-mp head: LDS-tiled GEMM + log_softmax ----------------

__launch_bounds__(256)
__global__ void head_kernel(const unsigned short* __restrict__ emb,
                            const float* __restrict__ Wp1,
                            const float* __restrict__ bp1,
                            const float* __restrict__ Wp2,
                            const float* __restrict__ bp2,
                            void* __restrict__ d_out, int N,
                            const int* __restrict__ flags) {
    __shared__ float Est[64][68];     // [k][row], relu'd
    __shared__ float W1s[64][64];     // [k][c]
    __shared__ float Tst[64][68];     // [c][row]
    __shared__ float W2s[64][OUTD];   // [c][o]
    __shared__ float b1s[64];
    __shared__ float b2s[OUTD];
    int tid = threadIdx.x;
    int row0 = blockIdx.x * 64;
    for (int i = tid; i < 64 * 64; i += 256) W1s[i >> 6][i & 63] = Wp1[i];
    for (int i = tid; i < 64 * OUTD; i += 256) W2s[i / OUTD][i % OUTD] = Wp2[i];
    if (tid < 64) b1s[tid] = bp1[tid];
    if (tid < OUTD) b2s[tid] = bp2[tid];
    for (int i = tid; i < 64 * 32; i += 256) {
        int r = i >> 5, kk = i & 31;
        int row = row0 + r;
        unsigned int u = (row < N) ? *(const unsigned int*)&emb[(size_t)row * 64 + kk * 2] : 0u;
        Est[kk * 2][r]     = fmaxf(bf2f(u & 0xffffu), 0.f);
        Est[kk * 2 + 1][r] = fmaxf(bf2f(u >> 16), 0.f);
    }
    __syncthreads();
    // phase 1
    {
        int rg = tid >> 4, cg = tid & 15;
        int r = rg * 4, c = cg * 4;
        float acc[4][4];
        #pragma unroll
        for (int i = 0; i < 4; ++i)
            #pragma unroll
            for (int jj = 0; jj < 4; ++jj) acc[i][jj] = b1s[c + jj];
        #pragma unroll 4
        for (int k = 0; k < 64; ++k) {
            float4 a = *(const float4*)&Est[k][r];
            float4 wv = *(const float4*)&W1s[k][c];
            acc[0][0] += a.x * wv.x; acc[0][1] += a.x * wv.y; acc[0][2] += a.x * wv.z; acc[0][3] += a.x * wv.w;
            acc[1][0] += a.y * wv.x; acc[1][1] += a.y * wv.y; acc[1][2] += a.y * wv.z; acc[1][3] += a.y * wv.w;
            acc[2][0] += a.z * wv.x; acc[2][1] += a.z * wv.y; acc[2][2] += a.z * wv.z; acc[2][3] += a.z * wv.w;
            acc[3][0] += a.w * wv.x; acc[3][1] += a.w * wv.y; acc[3][2] += a.w * wv.z; acc[3][3] += a.w * wv.w;
        }
        #pragma unroll
        for (int i = 0; i < 4; ++i)
            #pragma unroll
            for (int jj = 0; jj < 4; ++jj) Tst[c + jj][r + i] = acc[i][jj];
    }
    __syncthreads();
    // phase 2 + 3
    int row = tid >> 2, tc = tid & 3, o0 = tc * 10;
    int node = row0 + row;
    float u[10];
    #pragma unroll
    for (int o = 0; o < 10; ++o) u[o] = b2s[o0 + o];
    for (int c2 = 0; c2 < 64; ++c2) {
        float tv = Tst[c2][row];
        const float2* wp = (const float2*)&W2s[c2][o0];
        #pragma unroll
        for (int o2 = 0; o2 < 5; ++o2) {
            float2 wv = wp[o2];
            u[o2 * 2]     += tv * wv.x;
            u[o2 * 2 + 1] += tv * wv.y;
        }
    }
    float mx = u[0];
    #pragma unroll
    for (int o = 1; o < 10; ++o) mx = fmaxf(mx, u[o]);
    mx = fmaxf(mx, __shfl_xor(mx, 1, 64));
    mx = fmaxf(mx, __shfl_xor(mx, 2, 64));
    float sum = 0.f;
    #pragma unroll
    for (int o = 0; o < 10; ++o) sum += __expf(u[o] - mx);
    sum += __shfl_xor(sum, 1, 64);
    sum += __shfl_xor(sum, 2, 64);
    float lse = mx + __logf(sum);
    if (node < N) {
        if (flags[0]) {
            float* base = (float*)d_out + (size_t)N * HID2;
            float* op = base + (size_t)node * OUTD + o0;
            #pragma unroll
            for (int o = 0; o < 10; ++o) op[o] = u[o] - lse;
        } else {
            unsigned short* base = (unsigned short*)d_out + (size_t)N * HID2;
            unsigned int* op = (unsigned int*)(base + (size_t)node * OUTD + o0);
            #pragma unroll
            for (int o2 = 0; o2 < 5; ++o2)
                op[o2] = packbf(u[o2 * 2] - lse, u[o2 * 2 + 1] - lse);
        }
    }
}

// ---------------- launch ----------------

extern "C" void kernel_launch(void* const* d_in, const int* in_sizes, int n_in,
                              void* d_out, int out_size, void* d_ws, size_t ws_size,
                              hipStream_t stream) {
    const unsigned short* xu = (const unsigned short*)d_in[0];
    const int*            ei = (const int*)d_in[1];

    const int N = in_sizes[0] / DIN;   // 50000
    const int E = in_sizes[1] / 2;     // 800000
    const int NW = (N + 1) / 2;        // packed histogram words per chunk

    size_t off = 0;
    auto take = [&](size_t bytes) {
        size_t cur = off;
        off += (bytes + 255) & ~(size_t)255;
        return cur;
    };
    char* ws = (char*)d_ws;
    int*   flags   = (int*)  (ws + take(256));
    int*   cnt     = (int*)  (ws + take((size_t)N * 4));
    float* dinv    = (float*)(ws + take((size_t)N * 4));
    int*   indptr  = (int*)  (ws + take((size_t)(N + 1) * 4));
    int*   pos     = (int*)  (ws + take((size_t)E * 4));
    int2*  csr_sn  = (int2*) (ws + take((size_t)E * 8));
    int*   bsum    = (int*)  (ws + take(((size_t)N / 256 + 4) * 4));
    unsigned int* hist  = (unsigned int*)(ws + take((size_t)NCHUNK * NW * 4));
    unsigned int* basev = (unsigned int*)(ws + take((size_t)NCHUNK * NW * 4));
    unsigned short* wbf = (unsigned short*)(ws + take(32768 * 2));
    float*          wf  = (float*)         (ws + take(8192 * 4));
    unsigned short* hbuf = (unsigned short*)(ws + take((size_t)N * DIN * 2));
    unsigned short* abuf = (unsigned short*)(ws + take((size_t)N * DIN * 2));
    (void)ws_size; (void)n_in; (void)out_size;

    const int TB = 256;
    dim3 blk(TB);
    const int NB = (N + 255) / 256;          // 196 (must be <= 256 for emit scan)
    const int PB = (NW + 255) / 256;         // 98 phaseB blocks

    // weight conversion descriptor (consumed by phaseB fat blocks)
    WCvt wc;
    int bfoff = 0, foff = 0;
    int offs[14];
    const int wcols[14] = {HID1, 0, HID2, 0, HID2, 0, 0, 0, 0, 0, 0, 0, 0, 0};
    for (int a = 0; a < 14; ++a) {
        int idx = a + 2;
        wc.p[a] = d_in[idx];
        wc.sz[a] = in_sizes[idx];
        int tobf = (idx == 2 || idx == 4 || idx == 6) ? 1 : 0;
        wc.tobf[a] = tobf;
        wc.cols[a] = tobf ? wcols[a] : 1;
        if (tobf) { wc.off[a] = bfoff; bfoff += in_sizes[idx]; }
        else      { wc.off[a] = foff;  foff  += in_sizes[idx]; }
        offs[a] = wc.off[a];
    }

    posA_kernel<<<dim3(NCHUNK + 1), dim3(1024), 0, stream>>>(
        xu, ei, flags, pos, hist, E, N);
    phaseB_kernel<<<dim3(PB + 64), blk, 0, stream>>>(
        hist, basev, cnt, bsum, N, PB, wc, wbf, wf, flags);
    emit_kernel<<<dim3(NB), blk, 0, stream>>>(cnt, bsum, indptr, dinv, N, NB);
    scatter_kernel<<<dim3((E + 1023) / 1024), blk, 0, stream>>>(
        ei, indptr, pos, dinv, basev, csr_sn, E, N, flags);

    unsigned short* W1t = wbf + offs[0];   // [128][128] transposed
    unsigned short* W2t = wbf + offs[2];   // [64][128] transposed
    unsigned short* W3t = wbf + offs[4];   // [64][64] transposed
    float* b1f  = wf + offs[1];
    float* b2f  = wf + offs[3];
    float* b3f  = wf + offs[5];
    float* g1f  = wf + offs[6];
    float* be1f = wf + offs[7];
    float* g2f  = wf + offs[8];
    float* be2f = wf + offs[9];
    float* Wp1f = wf + offs[10];
    float* bp1f = wf + offs[11];
    float* Wp2f = wf + offs[12];
    float* bp2f = wf + offs[13];

    const int MMG = (N + 63) / 64;
    const int AGG = (N + 3) / 4;

    // layer 1: single dual-dtype launch (uniform branch on flags[0])
    mm_dual_kernel<DIN, HID1><<<dim3(MMG), blk, 0, stream>>>(
        d_in[0], W1t, hbuf, N, flags);
    agg_kernel<HID1, true, false><<<dim3(AGG), blk, 0, stream>>>(
        hbuf, indptr, csr_sn, dinv, b1f, g1f, be1f, abuf, nullptr, N, flags);

    // layer 2
    mm_bf_kernel<HID1, HID2><<<dim3(MMG), blk, 0, stream>>>(abuf, W2t, hbuf, N);
    agg_kernel<HID2, true, false><<<dim3(AGG), blk, 0, stream>>>(
        hbuf, indptr, csr_sn, dinv, b2f, g2f, be2f, abuf, nullptr, N, flags);

    // layer 3 -> emb
    mm_bf_kernel<HID2, HID2><<<dim3(MMG), blk, 0, stream>>>(abuf, W3t, hbuf, N);
    agg_kernel<HID2, false, true><<<dim3(AGG), blk, 0, stream>>>(
        hbuf, indptr, csr_sn, dinv, b3f, nullptr, nullptr, abuf, d_out, N, flags);

    // head
    head_kernel<<<dim3((N + 63) / 64), blk, 0, stream>>>(
        abuf, Wp1f, bp1f, Wp2f, bp2f, d_out, N, flags);
}

// Round 9
// 275.588 us; speedup vs baseline: 1.1272x; 1.1272x over previous
//
#include <hip/hip_runtime.h>
#include <hip/hip_bf16.h>

#define DIN 128
#define HID1 128
#define HID2 64
#define OUTD 40
#define NCHUNK 128  // edge chunks for LDS-histogram CSR build (6250 edges/chunk)

typedef __attribute__((ext_vector_type(8))) short bf16x8;
typedef __attribute__((ext_vector_type(4))) float f32x4;

__device__ __forceinline__ float bf2f(unsigned int u) {
    union { unsigned int i; float f; } c;
    c.i = u << 16;
    return c.f;
}
__device__ __forceinline__ unsigned short f2bf(float f) {
    union { float f; unsigned int i; } c; c.f = f;
    unsigned int r = c.i + 0x7FFFu + ((c.i >> 16) & 1u);   // RNE
    return (unsigned short)(r >> 16);
}
__device__ __forceinline__ unsigned int packbf(float lo, float hi) {
    return (unsigned int)f2bf(lo) | ((unsigned int)f2bf(hi) << 16);
}

__device__ __forceinline__ int get_src(const int* ei, int E, int e, int e64) {
    return e64 ? ei[2 * e] : ei[e];
}
__device__ __forceinline__ int get_dst(const int* ei, int E, int e, int e64) {
    return e64 ? ei[2 * (E + e)] : ei[E + e];
}

// ---------------- weight conversion descriptor ----------------
struct WCvt {
    const void* p[14];
    int sz[14];
    int off[14];
    int tobf[14];
    int cols[14];
};

// ---------------- posA (+flags): CSR histogram, zero global atomics ----------------
__launch_bounds__(1024)
__global__ void posA_kernel(const unsigned short* __restrict__ xu,
                            const int* __restrict__ ei,
                            int* __restrict__ flags,
                            int* __restrict__ pos,
                            unsigned int* __restrict__ hist,
                            int E, int N) {
    __shared__ unsigned int h32[25000];          // (N+1)/2 words, N<=50000
    __shared__ int sh2[2];
    const int NW = (N + 1) >> 1;
    const int b = blockIdx.x;
    const int t = threadIdx.x;
    if (b < NCHUNK) {
        if (t == 0) sh2[0] = 0;
        for (int w = t; w < NW; w += 1024) h32[w] = 0u;
        __syncthreads();
        // local int64 detect: high words of int64 edge values are ~all zero
        int zodd = 0;
        for (int k = t; k < 1024; k += 1024)
            if (ei[2 * k + 1] == 0) zodd++;
        if (zodd) atomicAdd(&sh2[0], zodd);
        __syncthreads();
        const int e64 = (sh2[0] > 512) ? 1 : 0;
        const int CH = (E + NCHUNK - 1) / NCHUNK;
        const int lo = b * CH;
        int hi = lo + CH; if (hi > E) hi = E;
        for (int e = lo + t; e < hi; e += 1024) {
            int d = e64 ? ei[2 * (E + e)] : ei[E + e];
            if ((unsigned)d < (unsigned)N) {
                unsigned sh = (unsigned)(d & 1) << 4;
                unsigned old = atomicAdd(&h32[d >> 1], 1u << sh);
                pos[e] = (int)((old >> sh) & 0xffffu);
            } else {
                pos[e] = -1;
            }
        }
        __syncthreads();
        unsigned int* hb = hist + (size_t)b * NW;
        for (int w = t; w < NW; w += 1024) hb[w] = h32[w];
    } else {
        // flags for downstream kernels
        if (t < 2) sh2[t] = 0;
        __syncthreads();
        int bad = 0;
        for (int k = t; k < 2048; k += 1024) {
            float v = bf2f(xu[2 * k]);
            float a = fabsf(v);
            if (!(a <= 1e4f) || (v != 0.f && a < 1e-4f)) bad++;
        }
        int zodd = 0;
        for (int k = t; k < 1024; k += 1024)
            if (ei[2 * k + 1] == 0) zodd++;
        if (bad) atomicAdd(&sh2[0], bad);
        if (zodd) atomicAdd(&sh2[1], zodd);
        __syncthreads();
        if (t == 0) {
            flags[0] = (sh2[0] > 512) ? 1 : 0;
            flags[1] = (sh2[1] > 512) ? 1 : 0;
        }
    }
}

// phaseB (+wcvt fat blocks): per-node exclusive scan across chunks -> basev, cnt;
// reduces its 512-node range into bsum entries 2b, 2b+1. basev PACKED 2x16-bit.
// blocks >= PB: weight conversion (tobf=1 -> bf16 arena TRANSPOSED; else f32 arena).
__launch_bounds__(256)
__global__ void phaseB_kernel(const unsigned int* __restrict__ hist,
                              unsigned int* __restrict__ basev,
                              int* __restrict__ cnt, int* __restrict__ bsum,
                              int N, int PB,
                              WCvt wc, unsigned short* __restrict__ wbf,
                              float* __restrict__ wf,
                              const int* __restrict__ flags) {
    __shared__ int red[256];
    const int NW = (N + 1) >> 1;
    int t = threadIdx.x;
    int blk = blockIdx.x;
    if (blk < PB) {
        int w = blk * 256 + t;
        unsigned run0 = 0, run1 = 0;
        if (w < NW) {
            #pragma unroll 4
            for (int b = 0; b < NCHUNK; ++b) {
                unsigned u = hist[(size_t)b * NW + w];
                basev[(size_t)b * NW + w] = (run0 & 0xffffu) | (run1 << 16);
                run0 += u & 0xffffu;
                run1 += u >> 16;
            }
            cnt[2 * w] = (int)run0;
            if (2 * w + 1 < N) cnt[2 * w + 1] = (int)run1;
        }
        int tot = 0;
        if (w < NW) tot = (int)run0 + ((2 * w + 1 < N) ? (int)run1 : 0);
        red[t] = tot;
        __syncthreads();
        #pragma unroll
        for (int off = 64; off >= 1; off >>= 1) {
            if ((t & 127) < off) red[t] += red[t + off];
            __syncthreads();
        }
        if (t == 0) bsum[2 * blk] = red[0];
        if (t == 128) bsum[2 * blk + 1] = red[128];
    } else {
        int xf32 = flags[0];
        int stride = (gridDim.x - PB) * 256;
        int tid = (blk - PB) * 256 + t;
        for (int a = 0; a < 14; ++a) {
            const float* pf = (const float*)wc.p[a];
            const unsigned short* pb = (const unsigned short*)wc.p[a];
            int n = wc.sz[a], off = wc.off[a], tobf = wc.tobf[a];
            int cols = wc.cols[a];
            int rows = tobf ? (n / cols) : 0;
            for (int i = tid; i < n; i += stride) {
                float v = xf32 ? pf[i] : bf2f(pb[i]);
                if (tobf) {
                    int k = i / cols, m = i % cols;
                    wbf[off + m * rows + k] = f2bf(v);   // transposed
                } else {
                    wf[off + i] = v;
                }
            }
        }
    }
}

// atomic-free scatter: slot = indptr[dst] + basev[chunk][dst](packed u16) + pos[e].
__global__ void scatter_kernel(const int* __restrict__ ei, const int* __restrict__ indptr,
                               const int* __restrict__ pos, const float* __restrict__ dinv,
                               const unsigned int* __restrict__ basev,
                               int2* __restrict__ csr_sn,
                               int E, int N, const int* __restrict__ flags) {
    int e64 = flags[1];
    int CH = (E + NCHUNK - 1) / NCHUNK;
    int NW = (N + 1) >> 1;
    int base = (blockIdx.x * blockDim.x + threadIdx.x) * 4;
    #pragma unroll
    for (int u = 0; u < 4; ++u) {
        int e = base + u;
        if (e < E) {
            int p = pos[e];
            if (p >= 0) {
                int bb = e / CH;
                int d = get_dst(ei, E, e, e64);
                int s = get_src(ei, E, e, e64);
                if ((unsigned)s >= (unsigned)N) s = 0;
                float nrm = dinv[s] * dinv[d];
                unsigned bw = basev[(size_t)bb * NW + (d >> 1)];
                int bval = (d & 1) ? (int)(bw >> 16) : (int)(bw & 0xffffu);
                int slot = indptr[d] + bval + p;
                csr_sn[slot] = make_int2(s, __float_as_int(nrm));
            }
        }
    }
}

// ---------------- MFMA matmul: C[N,M](bf16) = A[N,K] x W[K,M](bf16) ----------------

template<typename AT>
__device__ __forceinline__ bf16x8 ld_afrag(const AT* p);
template<>
__device__ __forceinline__ bf16x8 ld_afrag<unsigned short>(const unsigned short* p) {
    return *(const bf16x8*)p;
}
template<>
__device__ __forceinline__ bf16x8 ld_afrag<float>(const float* p) {
    float4 a = *(const float4*)p;
    float4 b = *(const float4*)(p + 4);
    bf16x8 r;
    r[0] = (short)f2bf(a.x); r[1] = (short)f2bf(a.y);
    r[2] = (short)f2bf(a.z); r[3] = (short)f2bf(a.w);
    r[4] = (short)f2bf(b.x); r[5] = (short)f2bf(b.y);
    r[6] = (short)f2bf(b.z); r[7] = (short)f2bf(b.w);
    return r;
}

template<int K, int M, typename AT>
__device__ __forceinline__ void mm_body(const AT* __restrict__ A,
                                        const unsigned short* __restrict__ WT,
                                        unsigned short* __restrict__ C, int N,
                                        unsigned short (*Ws)[K + 8], int bx) {
    int tid = threadIdx.x;
    for (int idx = tid; idx < M * K / 8; idx += 256) {
        int r = idx / (K / 8), c8 = idx % (K / 8);
        *(uint4*)&Ws[r][c8 * 8] = *(const uint4*)&WT[r * K + c8 * 8];
    }
    __syncthreads();
    int w = tid >> 6, lane = tid & 63;
    int m = lane & 15, q = lane >> 4;
    int row_a = bx * 64 + w * 16 + m;
    if (row_a >= N) row_a = N - 1;              // clamp; garbage rows masked at store
    const AT* arow = A + (size_t)row_a * K;
    f32x4 acc[M / 16];
    #pragma unroll
    for (int t = 0; t < M / 16; ++t) acc[t] = (f32x4){0.f, 0.f, 0.f, 0.f};
    #pragma unroll
    for (int ks = 0; ks < K / 32; ++ks) {
        int k0 = ks * 32 + q * 8;
        bf16x8 a = ld_afrag<AT>(arow + k0);
        #pragma unroll
        for (int t = 0; t < M / 16; ++t) {
            bf16x8 b = *(const bf16x8*)&Ws[t * 16 + m][k0];
            acc[t] = __builtin_amdgcn_mfma_f32_16x16x32_bf16(a, b, acc[t], 0, 0, 0);
        }
    }
    int rbase = bx * 64 + w * 16 + q * 4;
    #pragma unroll
    for (int reg = 0; reg < 4; ++reg) {
        int row = rbase + reg;
        if (row < N) {
            #pragma unroll
            for (int t = 0; t < M / 16; ++t)
                C[(size_t)row * M + t * 16 + m] = f2bf(acc[t][reg]);
        }
    }
}

// FUSED emit + layer-1 dual-dtype mm (independent work, one dispatch):
// blocks 0..NB-1: emit with inline bscan (scan bsum<=256 in LDS, write indptr+dinv).
// blocks NB.. : mm1 (needs only flags/W1t/x, all ready after phaseB).
// Shared LDS: mm's Ws buffer doubles as emit's two 256-int scan arrays.
template<int K, int M>
__launch_bounds__(256)
__global__ void emit_mm_kernel(const int* __restrict__ cnt, const int* __restrict__ bsum,
                               int* __restrict__ indptr, float* __restrict__ dinv,
                               int N, int NB,
                               const void* __restrict__ A,
                               const unsigned short* __restrict__ WT,
                               unsigned short* __restrict__ C,
                               const int* __restrict__ flags) {
    __shared__ unsigned short Ws[M][K + 8];      // 34.8 KB (M=128,K=128); emit uses 2 KB of it
    int blk = blockIdx.x;
    int t = threadIdx.x;
    if (blk < NB) {
        int* part = (int*)&Ws[0][0];
        int* sh   = part + 256;
        part[t] = (t < NB) ? bsum[t] : 0;
        __syncthreads();
        for (int off = 1; off < 256; off <<= 1) {
            int v = (t >= off) ? part[t - off] : 0;
            __syncthreads();
            part[t] += v;
            __syncthreads();
        }
        int bbase = (blk > 0) ? part[blk - 1] : 0;
        int total = part[255];
        int i = blk * 256 + t;
        int c = (i < N) ? cnt[i] : 0;
        sh[t] = c;
        __syncthreads();
        for (int off = 1; off < 256; off <<= 1) {
            int v = (t >= off) ? sh[t - off] : 0;
            __syncthreads();
            sh[t] += v;
            __syncthreads();
        }
        if (i < N) {
            int excl = sh[t] - c + bbase;
            indptr[i] = excl;
            dinv[i] = 1.0f / sqrtf((float)(c + 1));   // +1 self loop
        }
        if (blk == NB - 1 && t == 0) indptr[N] = total;
    } else {
        int bx = blk - NB;
        if (flags[0]) mm_body<K, M, float>((const float*)A, WT, C, N, Ws, bx);
        else          mm_body<K, M, unsigned short>((const unsigned short*)A, WT, C, N, Ws, bx);
    }
}

// layers 2/3: always bf16 input
template<int K, int M>
__launch_bounds__(256)
__global__ void mm_bf_kernel(const unsigned short* __restrict__ A,
                             const unsigned short* __restrict__ WT,
                             unsigned short* __restrict__ C, int N) {
    __shared__ unsigned short Ws[M][K + 8];
    mm_body<K, M, unsigned short>(A, WT, C, N, Ws, blockIdx.x);
}

// ---------------- aggregation + optional ReLU/LN ----------------
// 4 NODES PER WAVE: wave = 4 independent 16-lane groups, one node each (R7/R2
// proved 1-node/wave loses ~32us to 4x instruction-stream deflation).
// 32-EDGE STAGING + 8-DEEP GATHER ILP + ZERO-NORM PADDING (R6 best config).

template<int VPL>
__device__ __forceinline__ void gacc1(float* acc, const unsigned short* r, float n) {
    if constexpr (VPL == 8) {
        uint4 u = *(const uint4*)r;
        acc[0] += bf2f(u.x & 0xffffu) * n; acc[1] += bf2f(u.x >> 16) * n;
        acc[2] += bf2f(u.y & 0xffffu) * n; acc[3] += bf2f(u.y >> 16) * n;
        acc[4] += bf2f(u.z & 0xffffu) * n; acc[5] += bf2f(u.z >> 16) * n;
        acc[6] += bf2f(u.w & 0xffffu) * n; acc[7] += bf2f(u.w >> 16) * n;
    } else {
        uint2 u = *(const uint2*)r;
        acc[0] += bf2f(u.x & 0xffffu) * n; acc[1] += bf2f(u.x >> 16) * n;
        acc[2] += bf2f(u.y & 0xffffu) * n; acc[3] += bf2f(u.y >> 16) * n;
    }
}

// 8 rows, all loads issued before any accumulation (8-deep MLP per lane)
template<int VPL>
__device__ __forceinline__ void gacc8(float* acc,
                                      const unsigned short* const* rp,
                                      const float* nv) {
    if constexpr (VPL == 8) {
        uint4 u[8];
        #pragma unroll
        for (int i = 0; i < 8; ++i) u[i] = *(const uint4*)rp[i];
        #pragma unroll
        for (int i = 0; i < 8; ++i) {
            float n = nv[i];
            acc[0] += bf2f(u[i].x & 0xffffu) * n; acc[1] += bf2f(u[i].x >> 16) * n;
            acc[2] += bf2f(u[i].y & 0xffffu) * n; acc[3] += bf2f(u[i].y >> 16) * n;
            acc[4] += bf2f(u[i].z & 0xffffu) * n; acc[5] += bf2f(u[i].z >> 16) * n;
            acc[6] += bf2f(u[i].w & 0xffffu) * n; acc[7] += bf2f(u[i].w >> 16) * n;
        }
    } else {
        uint2 u[8];
        #pragma unroll
        for (int i = 0; i < 8; ++i) u[i] = *(const uint2*)rp[i];
        #pragma unroll
        for (int i = 0; i < 8; ++i) {
            float n = nv[i];
            acc[0] += bf2f(u[i].x & 0xffffu) * n; acc[1] += bf2f(u[i].x >> 16) * n;
            acc[2] += bf2f(u[i].y & 0xffffu) * n; acc[3] += bf2f(u[i].y >> 16) * n;
        }
    }
}

template<int H, bool RELU_LN, bool EMB>
__launch_bounds__(256)
__global__ void agg_kernel(const unsigned short* __restrict__ h,
                           const int* __restrict__ indptr,
                           const int2* __restrict__ csr_sn,
                           const float* __restrict__ dinv,
                           const float* __restrict__ bias,
                           const float* __restrict__ gamma,
                           const float* __restrict__ beta,
                           unsigned short* __restrict__ out,
                           void* __restrict__ out_emb,
                           int N, const int* __restrict__ flags) {
    constexpr int VPL = H / 16;                 // 8 (H=128), 4 (H=64)
    __shared__ int2 lsn[4][4][32];              // [wave][group][idx]
    int w = threadIdx.x >> 6;
    int lane = threadIdx.x & 63;
    int g = lane >> 4;                          // group = node within wave
    int idx = lane & 15;
    int node = blockIdx.x * 16 + w * 4 + g;
    bool active = node < N;
    int nd = active ? node : N - 1;             // clamp; inactive groups never store
    float di = dinv[nd];
    int c0 = idx * VPL;
    float acc[VPL];
    #pragma unroll
    for (int v = 0; v < VPL; ++v) acc[v] = 0.f;
    // self loop (full group covers the row once)
    gacc1<VPL>(acc, h + (size_t)nd * H + c0, di * di);
    int beg = indptr[nd], end = indptr[nd + 1];
    for (int base = beg; base < end; base += 32) {
        int m = end - base; if (m > 32) m = 32;
        // zero-norm padding: all 32 entries valid every staging round
        lsn[w][g][idx]      = (idx < m)      ? csr_sn[base + idx]      : make_int2(0, 0);
        lsn[w][g][idx + 16] = (idx + 16 < m) ? csr_sn[base + idx + 16] : make_int2(0, 0);
        // same-wave LDS write->read: ordered, no barrier
        int rounds = (m + 7) >> 3;
        int j = 0;
        for (int rr = 0; rr < rounds; ++rr, j += 8) {
            const unsigned short* rp[8];
            float nv[8];
            #pragma unroll
            for (int i = 0; i < 8; ++i) {
                int2 e = lsn[w][g][j + i];
                rp[i] = h + (size_t)e.x * H + c0;
                nv[i] = __int_as_float(e.y);
            }
            gacc8<VPL>(acc, rp, nv);
        }
    }
    #pragma unroll
    for (int v = 0; v < VPL; ++v) acc[v] += bias[c0 + v];
    if constexpr (RELU_LN) {
        #pragma unroll
        for (int v = 0; v < VPL; ++v) acc[v] = fmaxf(acc[v], 0.f);
        float s = 0.f, sq = 0.f;
        #pragma unroll
        for (int v = 0; v < VPL; ++v) { s += acc[v]; sq += acc[v] * acc[v]; }
        #pragma unroll
        for (int off = 8; off >= 1; off >>= 1) {   // stays inside the 16-lane group
            s += __shfl_xor(s, off, 64);
            sq += __shfl_xor(sq, off, 64);
        }
        float mu = s * (1.0f / H);
        float var = fmaxf(sq * (1.0f / H) - mu * mu, 0.f);
        float inv = 1.0f / sqrtf(var + 1e-5f);
        #pragma unroll
        for (int v = 0; v < VPL; ++v)
            acc[v] = (acc[v] - mu) * inv * gamma[c0 + v] + beta[c0 + v];
    }
    if (active) {
        unsigned short* orow = out + (size_t)node * H + c0;
        if constexpr (VPL == 8) {
            uint4 p;
            p.x = packbf(acc[0], acc[1]); p.y = packbf(acc[2], acc[3]);
            p.z = packbf(acc[4], acc[5]); p.w = packbf(acc[6], acc[7]);
            *(uint4*)orow = p;
        } else {
            uint2 p; p.x = packbf(acc[0], acc[1]); p.y = packbf(acc[2], acc[3]);
            *(uint2*)orow = p;
        }
        if constexpr (EMB) {
            if (flags[0]) {
                float* o = (float*)out_emb + (size_t)node * H + c0;
                #pragma unroll
                for (int v4 = 0; v4 < VPL / 4; ++v4)
                    *(float4*)(o + v4 * 4) = make_float4(acc[v4 * 4], acc[v4 * 4 + 1],
                                                         acc[v4 * 4 + 2], acc[v4 * 4 + 3]);
            } else {
                unsigned short* o = (unsigned short*)out_emb + (size_t)node * H + c0;
                #pragma unroll
                for (int v2 = 0; v2 < VPL / 2; ++v2)
                    ((unsigned int*)o)[v2] = packbf(acc[v2 * 2], acc[v2 * 2 + 1]);
            }
        }
    }
}

// ---------------- post-mp head: LDS-tiled GEMM + log_softmax ----------------

__launch_bounds__(256)
__global__ void head_kernel(const unsigned short* __restrict__ emb,
                            const float* __restrict__ Wp1,
                            const float* __restrict__ bp1,
                            const float* __restrict__ Wp2,
                            const float* __restrict__ bp2,
                            void* __restrict__ d_out, int N,
                            const int* __restrict__ flags) {
    __shared__ float Est[64][68];     // [k][row], relu'd
    __shared__ float W1s[64][64];     // [k][c]
    __shared__ float Tst[64][68];     // [c][row]
    __shared__ float W2s[64][OUTD];   // [c][o]
    __shared__ float b1s[64];
    __shared__ float b2s[OUTD];
    int tid = threadIdx.x;
    int row0 = blockIdx.x * 64;
    for (int i = tid; i < 64 * 64; i += 256) W1s[i >> 6][i & 63] = Wp1[i];
    for (int i = tid; i < 64 * OUTD; i += 256) W2s[i / OUTD][i % OUTD] = Wp2[i];
    if (tid < 64) b1s[tid] = bp1[tid];
    if (tid < OUTD) b2s[tid] = bp2[tid];
    for (int i = tid; i < 64 * 32; i += 256) {
        int r = i >> 5, kk = i & 31;
        int row = row0 + r;
        unsigned int u = (row < N) ? *(const unsigned int*)&emb[(size_t)row * 64 + kk * 2] : 0u;
        Est[kk * 2][r]     = fmaxf(bf2f(u & 0xffffu), 0.f);
        Est[kk * 2 + 1][r] = fmaxf(bf2f(u >> 16), 0.f);
    }
    __syncthreads();
    // phase 1
    {
        int rg = tid >> 4, cg = tid & 15;
        int r = rg * 4, c = cg * 4;
        float acc[4][4];
        #pragma unroll
        for (int i = 0; i < 4; ++i)
            #pragma unroll
            for (int jj = 0; jj < 4; ++jj) acc[i][jj] = b1s[c + jj];
        #pragma unroll 4
        for (int k = 0; k < 64; ++k) {
            float4 a = *(const float4*)&Est[k][r];
            float4 wv = *(const float4*)&W1s[k][c];
            acc[0][0] += a.x * wv.x; acc[0][1] += a.x * wv.y; acc[0][2] += a.x * wv.z; acc[0][3] += a.x * wv.w;
            acc[1][0] += a.y * wv.x; acc[1][1] += a.y * wv.y; acc[1][2] += a.y * wv.z; acc[1][3] += a.y * wv.w;
            acc[2][0] += a.z * wv.x; acc[2][1] += a.z * wv.y; acc[2][2] += a.z * wv.z; acc[2][3] += a.z * wv.w;
            acc[3][0] += a.w * wv.x; acc[3][1] += a.w * wv.y; acc[3][2] += a.w * wv.z; acc[3][3] += a.w * wv.w;
        }
        #pragma unroll
        for (int i = 0; i < 4; ++i)
            #pragma unroll
            for (int jj = 0; jj < 4; ++jj) Tst[c + jj][r + i] = acc[i][jj];
    }
    __syncthreads();
    // phase 2 + 3
    int row = tid >> 2, tc = tid & 3, o0 = tc * 10;
    int node = row0 + row;
    float u[10];
    #pragma unroll
    for (int o = 0; o < 10; ++o) u[o] = b2s[o0 + o];
    for (int c2 = 0; c2 < 64; ++c2) {
        float tv = Tst[c2][row];
        const float2* wp = (const float2*)&W2s[c2][o0];
        #pragma unroll
        for (int o2 = 0; o2 < 5; ++o2) {
            float2 wv = wp[o2];
            u[o2 * 2]     += tv * wv.x;
            u[o2 * 2 + 1] += tv * wv.y;
        }
    }
    float mx = u[0];
    #pragma unroll
    for (int o = 1; o < 10; ++o) mx = fmaxf(mx, u[o]);
    mx = fmaxf(mx, __shfl_xor(mx, 1, 64));
    mx = fmaxf(mx, __shfl_xor(mx, 2, 64));
    float sum = 0.f;
    #pragma unroll
    for (int o = 0; o < 10; ++o) sum += __expf(u[o] - mx);
    sum += __shfl_xor(sum, 1, 64);
    sum += __shfl_xor(sum, 2, 64);
    float lse = mx + __logf(sum);
    if (node < N) {
        if (flags[0]) {
            float* base = (float*)d_out + (size_t)N * HID2;
            float* op = base + (size_t)node * OUTD + o0;
            #pragma unroll
            for (int o = 0; o < 10; ++o) op[o] = u[o] - lse;
        } else {
            unsigned short* base = (unsigned short*)d_out + (size_t)N * HID2;
            unsigned int* op = (unsigned int*)(base + (size_t)node * OUTD + o0);
            #pragma unroll
            for (int o2 = 0; o2 < 5; ++o2)
                op[o2] = packbf(u[o2 * 2] - lse, u[o2 * 2 + 1] - lse);
        }
    }
}

// ---------------- launch ----------------

extern "C" void kernel_launch(void* const* d_in, const int* in_sizes, int n_in,
                              void* d_out, int out_size, void* d_ws, size_t ws_size,
                              hipStream_t stream) {
    const unsigned short* xu = (const unsigned short*)d_in[0];
    const int*            ei = (const int*)d_in[1];

    const int N = in_sizes[0] / DIN;   // 50000
    const int E = in_sizes[1] / 2;     // 800000
    const int NW = (N + 1) / 2;        // packed histogram words per chunk

    size_t off = 0;
    auto take = [&](size_t bytes) {
        size_t cur = off;
        off += (bytes + 255) & ~(size_t)255;
        return cur;
    };
    char* ws = (char*)d_ws;
    int*   flags   = (int*)  (ws + take(256));
    int*   cnt     = (int*)  (ws + take((size_t)N * 4));
    float* dinv    = (float*)(ws + take((size_t)N * 4));
    int*   indptr  = (int*)  (ws + take((size_t)(N + 1) * 4));
    int*   pos     = (int*)  (ws + take((size_t)E * 4));
    int2*  csr_sn  = (int2*) (ws + take((size_t)E * 8));
    int*   bsum    = (int*)  (ws + take(((size_t)N / 256 + 4) * 4));
    unsigned int* hist  = (unsigned int*)(ws + take((size_t)NCHUNK * NW * 4));
    unsigned int* basev = (unsigned int*)(ws + take((size_t)NCHUNK * NW * 4));
    unsigned short* wbf = (unsigned short*)(ws + take(32768 * 2));
    float*          wf  = (float*)         (ws + take(8192 * 4));
    unsigned short* hbuf = (unsigned short*)(ws + take((size_t)N * DIN * 2));
    unsigned short* abuf = (unsigned short*)(ws + take((size_t)N * DIN * 2));
    (void)ws_size; (void)n_in; (void)out_size;

    const int TB = 256;
    dim3 blk(TB);
    const int NB = (N + 255) / 256;          // 196 (must be <= 256 for emit scan)
    const int PB = (NW + 255) / 256;         // 98 phaseB blocks
    const int MMG = (N + 63) / 64;           // 782 mm blocks

    // weight conversion descriptor (consumed by phaseB fat blocks)
    WCvt wc;
    int bfoff = 0, foff = 0;
    int offs[14];
    const int wcols[14] = {HID1, 0, HID2, 0, HID2, 0, 0, 0, 0, 0, 0, 0, 0, 0};
    for (int a = 0; a < 14; ++a) {
        int idx = a + 2;
        wc.p[a] = d_in[idx];
        wc.sz[a] = in_sizes[idx];
        int tobf = (idx == 2 || idx == 4 || idx == 6) ? 1 : 0;
        wc.tobf[a] = tobf;
        wc.cols[a] = tobf ? wcols[a] : 1;
        if (tobf) { wc.off[a] = bfoff; bfoff += in_sizes[idx]; }
        else      { wc.off[a] = foff;  foff  += in_sizes[idx]; }
        offs[a] = wc.off[a];
    }

    unsigned short* W1t = wbf + offs[0];   // [128][128] transposed
    unsigned short* W2t = wbf + offs[2];   // [64][128] transposed
    unsigned short* W3t = wbf + offs[4];   // [64][64] transposed
    float* b1f  = wf + offs[1];
    float* b2f  = wf + offs[3];
    float* b3f  = wf + offs[5];
    float* g1f  = wf + offs[6];
    float* be1f = wf + offs[7];
    float* g2f  = wf + offs[8];
    float* be2f = wf + offs[9];
    float* Wp1f = wf + offs[10];
    float* bp1f = wf + offs[11];
    float* Wp2f = wf + offs[12];
    float* bp2f = wf + offs[13];

    posA_kernel<<<dim3(NCHUNK + 1), dim3(1024), 0, stream>>>(
        xu, ei, flags, pos, hist, E, N);
    phaseB_kernel<<<dim3(PB + 64), blk, 0, stream>>>(
        hist, basev, cnt, bsum, N, PB, wc, wbf, wf, flags);
    // fused: emit (blocks 0..NB-1) + layer-1 mm (blocks NB..NB+MMG-1)
    emit_mm_kernel<DIN, HID1><<<dim3(NB + MMG), blk, 0, stream>>>(
        cnt, bsum, indptr, dinv, N, NB, d_in[0], W1t, hbuf, flags);
    scatter_kernel<<<dim3((E + 1023) / 1024), blk, 0, stream>>>(
        ei, indptr, pos, dinv, basev, csr_sn, E, N, flags);

    const int AGG = (N + 15) / 16;

    agg_kernel<HID1, true, false><<<dim3(AGG), blk, 0, stream>>>(
        hbuf, indptr, csr_sn, dinv, b1f, g1f, be1f, abuf, nullptr, N, flags);

    // layer 2
    mm_bf_kernel<HID1, HID2><<<dim3(MMG), blk, 0, stream>>>(abuf, W2t, hbuf, N);
    agg_kernel<HID2, true, false><<<dim3(AGG), blk, 0, stream>>>(
        hbuf, indptr, csr_sn, dinv, b2f, g2f, be2f, abuf, nullptr, N, flags);

    // layer 3 -> emb
    mm_bf_kernel<HID2, HID2><<<dim3(MMG), blk, 0, stream>>>(abuf, W3t, hbuf, N);
    agg_kernel<HID2, false, true><<<dim3(AGG), blk, 0, stream>>>(
        hbuf, indptr, csr_sn, dinv, b3f, nullptr, nullptr, abuf, d_out, N, flags);

    // head
    head_kernel<<<dim3((N + 63) / 64), blk, 0, stream>>>(
        abuf, Wp1f, bp1f, Wp2f, bp2f, d_out, N, flags);
}